// Round 5
// baseline (88.526 us; speedup 1.0000x reference)
//
#include <hip/hip_runtime.h>

#define NB 8
#define LQ 4096
#define SK 4096
#define NH 8
#define DD 64
#define NPAIR (NB*NH)        // 64 (n,h) pairs
#define KVSZ (DD*DD + DD)    // 4160: 64x64 KV + 64 Ksum
#define VSP 2                // v-split: each block computes 32 of 64 v-cols

typedef short v8s __attribute__((ext_vector_type(8)));   // 8 bf16 MFMA operand
typedef float v4f __attribute__((ext_vector_type(4)));   // MFMA accumulator
union U8 { v8s s; unsigned int u[4]; };

__device__ __forceinline__ float fmap(float x) {
    return x > 0.f ? x + 1.f : __expf(x);   // elu+1
}
__device__ __forceinline__ unsigned short bf_hi(float x) {  // RNE fp32->bf16
    unsigned int u = __float_as_uint(x);
    return (unsigned short)((u + 0x7FFFu + ((u >> 16) & 1u)) >> 16);
}
__device__ __forceinline__ float bf_f(unsigned short b) {
    return __uint_as_float(((unsigned int)b) << 16);
}
// plane index for (row d, s-pair sp): bijective xor of bit4 with d-bit2.
// writes: 2-way max (free); b128 fragment reads: 8 distinct bank-quads (optimal).
__device__ __forceinline__ int swzp(int d, int sp) {
    return (d * 16 + sp) ^ (((d >> 2) & 1) << 4);
}
#define MFMA(A, B, C) __builtin_amdgcn_mfma_f32_16x16x32_bf16((A), (B), (C), 0, 0, 0)

// ---------------- Phase 1: partial KV = K^T V (+ ones-col => Ksum) via MFMA --------
// Per (pair, s-chunk, v-half) block; 2 waves, wave-private tiles, no main-loop barriers.
// LDS planes hold hi/lo bf16 s-pair-packed, d-major: fragment = 1 ds_read_b128.
__global__ __launch_bounds__(128, 3) void kv_partial_kernel(
    const float* __restrict__ K, const float* __restrict__ V,
    const float* __restrict__ kvm, float* __restrict__ partial, int CH)
{
    int bx = blockIdx.x;
    int chunk = bx % CH;
    int vh    = (bx / CH) % VSP;
    int pair  = bx / (CH * VSP);
    int nb = pair >> 3, h = pair & 7;
    int tid = threadIdx.x, w = tid >> 6, lane = tid & 63;
    int g = lane >> 4, c16 = lane & 15;
    int sp = lane & 15, dq = lane >> 4;    // staging roles

    __shared__ unsigned int smem[2][3072];  // per wave: K hi[1024] lo[1024], V hi[512] lo[512]
    __shared__ float ksb[2][64];
    unsigned int* kpl = &smem[w][0];
    unsigned int* vpl = &smem[w][2048];

    v4f acc[4][2], ks4[4];
    v4f z4 = {0.f, 0.f, 0.f, 0.f};
#pragma unroll
    for (int i = 0; i < 4; ++i) {
        ks4[i] = z4; acc[i][0] = z4; acc[i][1] = z4;
    }
    U8 Bones;
#pragma unroll
    for (int p = 0; p < 4; ++p) Bones.u[p] = (c16 == 0) ? 0x3F803F80u : 0u;

    int SC = SK / CH;
    int tiles = SC >> 5;

    float4 kr[8], vr[4];
    float m0, m1;

    auto LOADG = [&](int it) {   // issue next tile's global loads into regs
        int s0 = chunk * SC + (it << 5);
        int row = nb * SK + s0 + 2 * sp;
        m0 = kvm[row]; m1 = kvm[row + 1];
        const float* kb = K + ((size_t)row * NH + h) * DD;
        const float* vb = V + ((size_t)row * NH + h) * DD + vh * 32;
#pragma unroll
        for (int c = 0; c < 4; ++c) {
            kr[2 * c]     = *(const float4*)(kb + dq * 4 + c * 16);
            kr[2 * c + 1] = *(const float4*)(kb + NH * DD + dq * 4 + c * 16);
        }
#pragma unroll
        for (int c = 0; c < 2; ++c) {
            vr[2 * c]     = *(const float4*)(vb + dq * 4 + c * 16);
            vr[2 * c + 1] = *(const float4*)(vb + NH * DD + dq * 4 + c * 16);
        }
    };

    auto PACKW = [&]() {         // pack hi/lo bf16 s-pairs, write planes (2-way max)
#pragma unroll
        for (int c = 0; c < 4; ++c) {
            float a0[4] = {kr[2*c].x, kr[2*c].y, kr[2*c].z, kr[2*c].w};
            float a1[4] = {kr[2*c+1].x, kr[2*c+1].y, kr[2*c+1].z, kr[2*c+1].w};
#pragma unroll
            for (int i = 0; i < 4; ++i) {
                float x0 = fmap(a0[i]) * m0, x1 = fmap(a1[i]) * m1;
                unsigned short h0 = bf_hi(x0), h1 = bf_hi(x1);
                int idx = swzp(dq * 4 + c * 16 + i, sp);
                kpl[idx] = (unsigned int)h0 | ((unsigned int)h1 << 16);
                kpl[1024 + idx] = (unsigned int)bf_hi(x0 - bf_f(h0)) |
                                  ((unsigned int)bf_hi(x1 - bf_f(h1)) << 16);
            }
        }
#pragma unroll
        for (int c = 0; c < 2; ++c) {
            float a0[4] = {vr[2*c].x, vr[2*c].y, vr[2*c].z, vr[2*c].w};
            float a1[4] = {vr[2*c+1].x, vr[2*c+1].y, vr[2*c+1].z, vr[2*c+1].w};
#pragma unroll
            for (int i = 0; i < 4; ++i) {
                float x0 = a0[i] * m0, x1 = a1[i] * m1;
                unsigned short h0 = bf_hi(x0), h1 = bf_hi(x1);
                int idx = swzp(dq * 4 + c * 16 + i, sp);
                vpl[idx] = (unsigned int)h0 | ((unsigned int)h1 << 16);
                vpl[512 + idx] = (unsigned int)bf_hi(x0 - bf_f(h0)) |
                                 ((unsigned int)bf_hi(x1 - bf_f(h1)) << 16);
            }
        }
    };

    auto COMPUTE = [&]() {       // 12 ds_read_b128 -> 32 MFMA, zero repack
        v8s bh[2], bl[2];
#pragma unroll
        for (int nn = 0; nn < 2; ++nn) {
            int vloc = 16 * nn + c16;
            int idx = (vloc * 16 + 4 * g) ^ (((vloc >> 2) & 1) << 4);
            bh[nn] = *(const v8s*)&vpl[idx];
            bl[nn] = *(const v8s*)&vpl[512 + idx];
        }
#pragma unroll
        for (int md = 0; md < 4; ++md) {
            int d = 16 * md + c16;
            int idx = (d * 16 + 4 * g) ^ (((d >> 2) & 1) << 4);
            v8s ah = *(const v8s*)&kpl[idx];
            v8s al = *(const v8s*)&kpl[1024 + idx];
            if (vh == 0) {                       // wave-uniform
                ks4[md] = MFMA(ah, Bones.s, ks4[md]);
                ks4[md] = MFMA(al, Bones.s, ks4[md]);
            }
#pragma unroll
            for (int nn = 0; nn < 2; ++nn) {
                acc[md][nn] = MFMA(ah, bh[nn], acc[md][nn]);
                acc[md][nn] = MFMA(al, bh[nn], acc[md][nn]);
                acc[md][nn] = MFMA(ah, bl[nn], acc[md][nn]);
            }
        }
    };

    LOADG(w);
    for (int it = w; it < tiles; it += 2) {
        PACKW();
        if (it + 2 < tiles) LOADG(it + 2);   // in flight under fragment reads + MFMA
        COMPUTE();
    }

    // ---- epilogue: cross-wave reduce, write partial ----
    float* dst = partial + ((size_t)chunk * NPAIR + pair) * KVSZ;
    if (vh == 0 && c16 == 0) {
#pragma unroll
        for (int md = 0; md < 4; ++md)
#pragma unroll
            for (int jj = 0; jj < 4; ++jj)
                ksb[w][16 * md + 4 * g + jj] = ks4[md][jj];
    }
    __syncthreads();   // waves done with plane reads; ksb visible
    if (vh == 0 && tid < 64) dst[4096 + tid] = ksb[0][tid] + ksb[1][tid];

    float* scr = (float*)&smem[0][0];   // overlay 16 KB scratch
#pragma unroll
    for (int md = 0; md < 4; ++md)
#pragma unroll
        for (int nn = 0; nn < 2; ++nn)
#pragma unroll
            for (int jj = 0; jj < 4; ++jj)
                scr[w * 2048 + (16 * md + 4 * g + jj) * 32 + 16 * nn + c16] = acc[md][nn][jj];
    __syncthreads();
    {
        int i0 = tid * 16;
#pragma unroll
        for (int e = 0; e < 4; ++e) {
            int idx = i0 + 4 * e;
            float4 x = *(float4*)&scr[idx];
            float4 y = *(float4*)&scr[2048 + idx];
            int d = idx >> 5, v = idx & 31;
            *(float4*)&dst[d * 64 + vh * 32 + v] =
                make_float4(x.x + y.x, x.y + y.y, x.z + y.z, x.w + y.w);
        }
    }
}

// ---------------- Phase 1b: reduce partials over chunks -----------------
__global__ __launch_bounds__(256) void kv_reduce_kernel(
    const float* __restrict__ partial, float* __restrict__ kvf, int CH)
{
    int i = blockIdx.x * 256 + threadIdx.x;
    if (i >= NPAIR * KVSZ) return;
    float s = 0.f;
    for (int c = 0; c < CH; ++c) s += partial[(size_t)c * NPAIR * KVSZ + i];
    kvf[i] = s;
}

// ---------------- Phase 2: out = (q.KV)/(q.Ksum + eps) via MFMA, no LDS --------
__global__ __launch_bounds__(256) void attn_out_kernel(
    const float* __restrict__ Q, const float* __restrict__ qm,
    const float* __restrict__ kvf, float* __restrict__ out)
{
    int bx = blockIdx.x;
    int pair = bx >> 4;            // 16 consecutive blocks share a pair (L2)
    int rb   = bx & 15;            // 256-row group
    int nb = pair >> 3, h = pair & 7;
    int lane = threadIdx.x & 63;
    int w    = threadIdx.x >> 6;
    int g    = lane >> 4;
    int c16  = lane & 15;

    const float* kvp = kvf + (size_t)pair * KVSZ;

    // ---- preload B fragments (hi only for KV; hi+lo for Ksum column) ----
    U8 Bh[2][4], Bkh[2], Bkl[2];
#pragma unroll
    for (int ks = 0; ks < 2; ++ks) {
#pragma unroll
        for (int nn = 0; nn < 4; ++nn) {
            unsigned short hs[8];
#pragma unroll
            for (int j = 0; j < 8; ++j)
                hs[j] = bf_hi(kvp[(32 * ks + 8 * g + j) * 64 + 16 * nn + c16]);
#pragma unroll
            for (int p = 0; p < 4; ++p)
                Bh[ks][nn].u[p] = (unsigned int)hs[2*p] | ((unsigned int)hs[2*p+1] << 16);
        }
        unsigned int kh[8], kl[8];
#pragma unroll
        for (int j = 0; j < 8; ++j) {
            float x = kvp[4096 + 32 * ks + 8 * g + j];
            unsigned short hh = bf_hi(x);
            kh[j] = hh;
            kl[j] = bf_hi(x - bf_f(hh));
        }
#pragma unroll
        for (int p = 0; p < 4; ++p) {
            Bkh[ks].u[p] = (c16 == 0) ? (kh[2*p] | (kh[2*p+1] << 16)) : 0u;
            Bkl[ks].u[p] = (c16 == 0) ? (kl[2*p] | (kl[2*p+1] << 16)) : 0u;
        }
    }

    v4f z4 = {0.f, 0.f, 0.f, 0.f};
#pragma unroll
    for (int it = 0; it < 4; ++it) {
        int row0 = rb * 256 + (w + 4 * it) * 16;
        int row  = row0 + c16;
        float qmv = qm[nb * LQ + row];
        const float* qrow = Q + ((size_t)((nb * LQ + row) * NH + h)) * DD;

        U8 Ah[2], Al[2];
#pragma unroll
        for (int ks = 0; ks < 2; ++ks) {
            float4 q0 = *(const float4*)(qrow + 8 * g + 32 * ks);
            float4 q1 = *(const float4*)(qrow + 8 * g + 32 * ks + 4);
            float qv[8] = {q0.x, q0.y, q0.z, q0.w, q1.x, q1.y, q1.z, q1.w};
            unsigned int pp[8];
#pragma unroll
            for (int j = 0; j < 8; ++j) {
                float x = fmap(qv[j]) * qmv;
                unsigned short hh = bf_hi(x);
                pp[j] = (unsigned int)hh | ((unsigned int)bf_hi(x - bf_f(hh)) << 16);
            }
#pragma unroll
            for (int p = 0; p < 4; ++p) {
                Ah[ks].u[p] = (pp[2*p] & 0xFFFFu) | (pp[2*p+1] << 16);
                Al[ks].u[p] = (pp[2*p] >> 16)     | (pp[2*p+1] & 0xFFFF0000u);
            }
        }

        v4f a0 = z4, a1 = z4, a2 = z4, a3 = z4, a4 = z4;
#pragma unroll
        for (int ks = 0; ks < 2; ++ks) {
            a0 = MFMA(Ah[ks].s, Bh[ks][0].s, a0);
            a1 = MFMA(Ah[ks].s, Bh[ks][1].s, a1);
            a2 = MFMA(Ah[ks].s, Bh[ks][2].s, a2);
            a3 = MFMA(Ah[ks].s, Bh[ks][3].s, a3);
            a0 = MFMA(Al[ks].s, Bh[ks][0].s, a0);
            a1 = MFMA(Al[ks].s, Bh[ks][1].s, a1);
            a2 = MFMA(Al[ks].s, Bh[ks][2].s, a2);
            a3 = MFMA(Al[ks].s, Bh[ks][3].s, a3);
            a4 = MFMA(Ah[ks].s, Bkh[ks].s, a4);
            a4 = MFMA(Al[ks].s, Bkh[ks].s, a4);
            a4 = MFMA(Ah[ks].s, Bkl[ks].s, a4);
        }

        int src = lane & 48;
#pragma unroll
        for (int jj = 0; jj < 4; ++jj) {
            float den = __shfl(a4[jj], src);
            float z = 1.f / (den + 1e-6f);
            size_t ob = ((size_t)((nb * LQ + row0 + 4 * g + jj) * NH + h)) * DD + c16;
            out[ob]      = a0[jj] * z;
            out[ob + 16] = a1[jj] * z;
            out[ob + 32] = a2[jj] * z;
            out[ob + 48] = a3[jj] * z;
        }
    }
}

extern "C" void kernel_launch(void* const* d_in, const int* in_sizes, int n_in,
                              void* d_out, int out_size, void* d_ws, size_t ws_size,
                              hipStream_t stream) {
    const float* Q   = (const float*)d_in[0];
    const float* K   = (const float*)d_in[1];
    const float* V   = (const float*)d_in[2];
    const float* qm  = (const float*)d_in[3];
    const float* kvm = (const float*)d_in[4];
    float* out = (float*)d_out;

    int CH = 16;
    while (CH > 1 && (size_t)(CH + 1) * NPAIR * KVSZ * sizeof(float) > ws_size) CH >>= 1;

    float* partial = (float*)d_ws;
    float* kvf = partial + (size_t)CH * NPAIR * KVSZ;

    kv_partial_kernel<<<dim3(NPAIR * CH * VSP), dim3(128), 0, stream>>>(K, V, kvm, partial, CH);
    kv_reduce_kernel<<<dim3((NPAIR * KVSZ + 255) / 256), dim3(256), 0, stream>>>(partial, kvf, CH);
    attn_out_kernel<<<dim3(NPAIR * 16), dim3(256), 0, stream>>>(Q, qm, kvf, out);
}

// Round 6
// 87.564 us; speedup vs baseline: 1.0110x; 1.0110x over previous
//
#include <hip/hip_runtime.h>

#define NB 8
#define LQ 4096
#define SK 4096
#define NH 8
#define DD 64
#define NPAIR (NB*NH)        // 64 (n,h) pairs
#define KVSZ (DD*DD + DD)    // 4160: 64x64 KV + 64 Ksum
#define VSP 2                // v-split: each block computes 32 of 64 v-cols
#define FRAGW 768            // uint4 words of prepacked fragments per pair (12KB)

typedef short v8s __attribute__((ext_vector_type(8)));   // 8 bf16 MFMA operand
typedef float v4f __attribute__((ext_vector_type(4)));   // MFMA accumulator
union U8 { v8s s; unsigned int u[4]; uint4 q; };

__device__ __forceinline__ float fmap(float x) {
    return x > 0.f ? x + 1.f : __expf(x);   // elu+1
}
__device__ __forceinline__ unsigned short bf_hi(float x) {  // RNE fp32->bf16
    unsigned int u = __float_as_uint(x);
    return (unsigned short)((u + 0x7FFFu + ((u >> 16) & 1u)) >> 16);
}
__device__ __forceinline__ float bf_f(unsigned short b) {
    return __uint_as_float(((unsigned int)b) << 16);
}
__device__ __forceinline__ int swzp(int d, int sp) {
    return (d * 16 + sp) ^ (((d >> 2) & 1) << 4);
}
#define MFMA(A, B, C) __builtin_amdgcn_mfma_f32_16x16x32_bf16((A), (B), (C), 0, 0, 0)

// ---------------- Phase 1: partial KV = K^T V (+ ones-col => Ksum) via MFMA --------
// (unchanged from round 5 — known good)
__global__ __launch_bounds__(128, 3) void kv_partial_kernel(
    const float* __restrict__ K, const float* __restrict__ V,
    const float* __restrict__ kvm, float* __restrict__ partial, int CH)
{
    int bx = blockIdx.x;
    int chunk = bx % CH;
    int vh    = (bx / CH) % VSP;
    int pair  = bx / (CH * VSP);
    int nb = pair >> 3, h = pair & 7;
    int tid = threadIdx.x, w = tid >> 6, lane = tid & 63;
    int g = lane >> 4, c16 = lane & 15;
    int sp = lane & 15, dq = lane >> 4;    // staging roles

    __shared__ unsigned int smem[2][3072];
    __shared__ float ksb[2][64];
    unsigned int* kpl = &smem[w][0];
    unsigned int* vpl = &smem[w][2048];

    v4f acc[4][2], ks4[4];
    v4f z4 = {0.f, 0.f, 0.f, 0.f};
#pragma unroll
    for (int i = 0; i < 4; ++i) {
        ks4[i] = z4; acc[i][0] = z4; acc[i][1] = z4;
    }
    U8 Bones;
#pragma unroll
    for (int p = 0; p < 4; ++p) Bones.u[p] = (c16 == 0) ? 0x3F803F80u : 0u;

    int SC = SK / CH;
    int tiles = SC >> 5;

    float4 kr[8], vr[4];
    float m0, m1;

    auto LOADG = [&](int it) {
        int s0 = chunk * SC + (it << 5);
        int row = nb * SK + s0 + 2 * sp;
        m0 = kvm[row]; m1 = kvm[row + 1];
        const float* kb = K + ((size_t)row * NH + h) * DD;
        const float* vb = V + ((size_t)row * NH + h) * DD + vh * 32;
#pragma unroll
        for (int c = 0; c < 4; ++c) {
            kr[2 * c]     = *(const float4*)(kb + dq * 4 + c * 16);
            kr[2 * c + 1] = *(const float4*)(kb + NH * DD + dq * 4 + c * 16);
        }
#pragma unroll
        for (int c = 0; c < 2; ++c) {
            vr[2 * c]     = *(const float4*)(vb + dq * 4 + c * 16);
            vr[2 * c + 1] = *(const float4*)(vb + NH * DD + dq * 4 + c * 16);
        }
    };

    auto PACKW = [&]() {
#pragma unroll
        for (int c = 0; c < 4; ++c) {
            float a0[4] = {kr[2*c].x, kr[2*c].y, kr[2*c].z, kr[2*c].w};
            float a1[4] = {kr[2*c+1].x, kr[2*c+1].y, kr[2*c+1].z, kr[2*c+1].w};
#pragma unroll
            for (int i = 0; i < 4; ++i) {
                float x0 = fmap(a0[i]) * m0, x1 = fmap(a1[i]) * m1;
                unsigned short h0 = bf_hi(x0), h1 = bf_hi(x1);
                int idx = swzp(dq * 4 + c * 16 + i, sp);
                kpl[idx] = (unsigned int)h0 | ((unsigned int)h1 << 16);
                kpl[1024 + idx] = (unsigned int)bf_hi(x0 - bf_f(h0)) |
                                  ((unsigned int)bf_hi(x1 - bf_f(h1)) << 16);
            }
        }
#pragma unroll
        for (int c = 0; c < 2; ++c) {
            float a0[4] = {vr[2*c].x, vr[2*c].y, vr[2*c].z, vr[2*c].w};
            float a1[4] = {vr[2*c+1].x, vr[2*c+1].y, vr[2*c+1].z, vr[2*c+1].w};
#pragma unroll
            for (int i = 0; i < 4; ++i) {
                float x0 = a0[i] * m0, x1 = a1[i] * m1;
                unsigned short h0 = bf_hi(x0), h1 = bf_hi(x1);
                int idx = swzp(dq * 4 + c * 16 + i, sp);
                vpl[idx] = (unsigned int)h0 | ((unsigned int)h1 << 16);
                vpl[512 + idx] = (unsigned int)bf_hi(x0 - bf_f(h0)) |
                                 ((unsigned int)bf_hi(x1 - bf_f(h1)) << 16);
            }
        }
    };

    auto COMPUTE = [&]() {
        v8s bh[2], bl[2];
#pragma unroll
        for (int nn = 0; nn < 2; ++nn) {
            int vloc = 16 * nn + c16;
            int idx = (vloc * 16 + 4 * g) ^ (((vloc >> 2) & 1) << 4);
            bh[nn] = *(const v8s*)&vpl[idx];
            bl[nn] = *(const v8s*)&vpl[512 + idx];
        }
#pragma unroll
        for (int md = 0; md < 4; ++md) {
            int d = 16 * md + c16;
            int idx = (d * 16 + 4 * g) ^ (((d >> 2) & 1) << 4);
            v8s ah = *(const v8s*)&kpl[idx];
            v8s al = *(const v8s*)&kpl[1024 + idx];
            if (vh == 0) {
                ks4[md] = MFMA(ah, Bones.s, ks4[md]);
                ks4[md] = MFMA(al, Bones.s, ks4[md]);
            }
#pragma unroll
            for (int nn = 0; nn < 2; ++nn) {
                acc[md][nn] = MFMA(ah, bh[nn], acc[md][nn]);
                acc[md][nn] = MFMA(al, bh[nn], acc[md][nn]);
                acc[md][nn] = MFMA(ah, bl[nn], acc[md][nn]);
            }
        }
    };

    LOADG(w);
    for (int it = w; it < tiles; it += 2) {
        PACKW();
        if (it + 2 < tiles) LOADG(it + 2);
        COMPUTE();
    }

    float* dst = partial + ((size_t)chunk * NPAIR + pair) * KVSZ;
    if (vh == 0 && c16 == 0) {
#pragma unroll
        for (int md = 0; md < 4; ++md)
#pragma unroll
            for (int jj = 0; jj < 4; ++jj)
                ksb[w][16 * md + 4 * g + jj] = ks4[md][jj];
    }
    __syncthreads();
    if (vh == 0 && tid < 64) dst[4096 + tid] = ksb[0][tid] + ksb[1][tid];

    float* scr = (float*)&smem[0][0];
#pragma unroll
    for (int md = 0; md < 4; ++md)
#pragma unroll
        for (int nn = 0; nn < 2; ++nn)
#pragma unroll
            for (int jj = 0; jj < 4; ++jj)
                scr[w * 2048 + (16 * md + 4 * g + jj) * 32 + 16 * nn + c16] = acc[md][nn][jj];
    __syncthreads();
    {
        int i0 = tid * 16;
#pragma unroll
        for (int e = 0; e < 4; ++e) {
            int idx = i0 + 4 * e;
            float4 x = *(float4*)&scr[idx];
            float4 y = *(float4*)&scr[2048 + idx];
            int d = idx >> 5, v = idx & 31;
            *(float4*)&dst[d * 64 + vh * 32 + v] =
                make_float4(x.x + y.x, x.y + y.y, x.z + y.z, x.w + y.w);
        }
    }
}

// ---------------- Phase 1b: reduce partials over chunks -----------------
__global__ __launch_bounds__(256) void kv_reduce_kernel(
    const float* __restrict__ partial, float* __restrict__ kvf, int CH)
{
    int i = blockIdx.x * 256 + threadIdx.x;
    if (i >= NPAIR * KVSZ) return;
    float s = 0.f;
    for (int c = 0; c < CH; ++c) s += partial[(size_t)c * NPAIR * KVSZ + i];
    kvf[i] = s;
}

// ---------------- Phase 1c: prepack B fragments (bf16) for attn_out --------
// Layout per pair: i4=0..7 -> Bh[ks=i4>>2][nn=i4&3]; i4=8,9 -> Bkh[0,1];
// i4=10,11 -> Bkl[0,1].  word[i4*64+lane] = uint4 (the 4 .u of that fragment).
__global__ __launch_bounds__(256) void kv_pack_kernel(
    const float* __restrict__ kvf, uint4* __restrict__ frag)
{
    int pair = blockIdx.x;
    int t = threadIdx.x;
    __shared__ float kvr[KVSZ];
    const float* src = kvf + (size_t)pair * KVSZ;
    for (int e = t; e < KVSZ / 4; e += 256)
        *(float4*)&kvr[4 * e] = *(const float4*)(src + 4 * e);
    __syncthreads();

    for (int e = t; e < FRAGW; e += 256) {
        int i4 = e >> 6, lane = e & 63;
        int g = lane >> 4, c16 = lane & 15;
        unsigned int wd[4];
        if (i4 < 8) {
            int ks = i4 >> 2, nn = i4 & 3;
#pragma unroll
            for (int p = 0; p < 4; ++p) {
                float x0 = kvr[(32 * ks + 8 * g + 2 * p) * 64 + 16 * nn + c16];
                float x1 = kvr[(32 * ks + 8 * g + 2 * p + 1) * 64 + 16 * nn + c16];
                wd[p] = (unsigned int)bf_hi(x0) | ((unsigned int)bf_hi(x1) << 16);
            }
        } else {
            int j = i4 - 8, ks = j & 1, lo = j >> 1;
#pragma unroll
            for (int p = 0; p < 4; ++p) {
                unsigned int wp = 0;
                if (c16 == 0) {
                    float x0 = kvr[4096 + 32 * ks + 8 * g + 2 * p];
                    float x1 = kvr[4096 + 32 * ks + 8 * g + 2 * p + 1];
                    unsigned short h0 = bf_hi(x0), h1 = bf_hi(x1);
                    if (lo)
                        wp = (unsigned int)bf_hi(x0 - bf_f(h0)) |
                             ((unsigned int)bf_hi(x1 - bf_f(h1)) << 16);
                    else
                        wp = (unsigned int)h0 | ((unsigned int)h1 << 16);
                }
                wd[p] = wp;
            }
        }
        uint4 o; o.x = wd[0]; o.y = wd[1]; o.z = wd[2]; o.w = wd[3];
        frag[(size_t)pair * FRAGW + e] = o;
    }
}

// ---------------- Phase 2: out = (q.KV)/(q.Ksum + eps) via MFMA, no LDS --------
// Prepacked B fragments (12 coalesced uint4 loads); Q register-prefetched
// one iteration ahead; 2048 blocks x 2 iterations.
__global__ __launch_bounds__(256) void attn_out_kernel(
    const float* __restrict__ Q, const float* __restrict__ qm,
    const uint4* __restrict__ frag, float* __restrict__ out)
{
    int bx = blockIdx.x;
    int pair = bx >> 5;            // 32 consecutive blocks share a pair (L2)
    int rb   = bx & 31;            // 128-row group
    int nb = pair >> 3, h = pair & 7;
    int lane = threadIdx.x & 63;
    int w    = threadIdx.x >> 6;
    int g    = lane >> 4;
    int c16  = lane & 15;

    const uint4* fb = frag + (size_t)pair * FRAGW;
    U8 Bh[2][4], Bkh[2], Bkl[2];
#pragma unroll
    for (int ks = 0; ks < 2; ++ks)
#pragma unroll
        for (int nn = 0; nn < 4; ++nn)
            Bh[ks][nn].q = fb[(ks * 4 + nn) * 64 + lane];
    Bkh[0].q = fb[8 * 64 + lane];
    Bkh[1].q = fb[9 * 64 + lane];
    Bkl[0].q = fb[10 * 64 + lane];
    Bkl[1].q = fb[11 * 64 + lane];

    float4 qA[2][4];
    float qmA[2];

    auto QLOAD = [&](int it, float4* qr, float& qmv) {
        int row = rb * 128 + (w + 4 * it) * 16 + c16;
        qmv = qm[nb * LQ + row];
        const float* qrow = Q + ((size_t)((nb * LQ + row) * NH + h)) * DD;
        qr[0] = *(const float4*)(qrow + 8 * g);
        qr[1] = *(const float4*)(qrow + 8 * g + 4);
        qr[2] = *(const float4*)(qrow + 8 * g + 32);
        qr[3] = *(const float4*)(qrow + 8 * g + 36);
    };

    v4f z4 = {0.f, 0.f, 0.f, 0.f};
    QLOAD(0, qA[0], qmA[0]);
#pragma unroll
    for (int it = 0; it < 2; ++it) {
        if (it == 0) QLOAD(1, qA[1], qmA[1]);   // prefetch under pack+MFMA
        const float4* qr = qA[it];
        float qmv = qmA[it];

        U8 Ah[2], Al[2];
#pragma unroll
        for (int ks = 0; ks < 2; ++ks) {
            float qv[8] = {qr[2*ks].x, qr[2*ks].y, qr[2*ks].z, qr[2*ks].w,
                           qr[2*ks+1].x, qr[2*ks+1].y, qr[2*ks+1].z, qr[2*ks+1].w};
            unsigned int pp[8];
#pragma unroll
            for (int j = 0; j < 8; ++j) {
                float x = fmap(qv[j]) * qmv;
                unsigned short hh = bf_hi(x);
                pp[j] = (unsigned int)hh | ((unsigned int)bf_hi(x - bf_f(hh)) << 16);
            }
#pragma unroll
            for (int p = 0; p < 4; ++p) {
                Ah[ks].u[p] = (pp[2*p] & 0xFFFFu) | (pp[2*p+1] << 16);
                Al[ks].u[p] = (pp[2*p] >> 16)     | (pp[2*p+1] & 0xFFFF0000u);
            }
        }

        v4f a0 = z4, a1 = z4, a2 = z4, a3 = z4, a4 = z4;
#pragma unroll
        for (int ks = 0; ks < 2; ++ks) {
            a0 = MFMA(Ah[ks].s, Bh[ks][0].s, a0);
            a1 = MFMA(Ah[ks].s, Bh[ks][1].s, a1);
            a2 = MFMA(Ah[ks].s, Bh[ks][2].s, a2);
            a3 = MFMA(Ah[ks].s, Bh[ks][3].s, a3);
            a0 = MFMA(Al[ks].s, Bh[ks][0].s, a0);
            a1 = MFMA(Al[ks].s, Bh[ks][1].s, a1);
            a2 = MFMA(Al[ks].s, Bh[ks][2].s, a2);
            a3 = MFMA(Al[ks].s, Bh[ks][3].s, a3);
            a4 = MFMA(Ah[ks].s, Bkh[ks].s, a4);
            a4 = MFMA(Al[ks].s, Bkh[ks].s, a4);
            a4 = MFMA(Ah[ks].s, Bkl[ks].s, a4);
        }

        int row0 = rb * 128 + (w + 4 * it) * 16;
        int src = lane & 48;
#pragma unroll
        for (int jj = 0; jj < 4; ++jj) {
            float den = __shfl(a4[jj], src);
            float z = 1.f / (den + 1e-6f);
            size_t ob = ((size_t)((nb * LQ + row0 + 4 * g + jj) * NH + h)) * DD + c16;
            out[ob]      = a0[jj] * z;
            out[ob + 16] = a1[jj] * z;
            out[ob + 32] = a2[jj] * z;
            out[ob + 48] = a3[jj] * z;
        }
    }
}

extern "C" void kernel_launch(void* const* d_in, const int* in_sizes, int n_in,
                              void* d_out, int out_size, void* d_ws, size_t ws_size,
                              hipStream_t stream) {
    const float* Q   = (const float*)d_in[0];
    const float* K   = (const float*)d_in[1];
    const float* V   = (const float*)d_in[2];
    const float* qm  = (const float*)d_in[3];
    const float* kvm = (const float*)d_in[4];
    float* out = (float*)d_out;

    int CH = 16;
    while (CH > 1 && (size_t)(CH + 1) * NPAIR * KVSZ * sizeof(float) > ws_size) CH >>= 1;

    float* partial = (float*)d_ws;
    float* kvf = partial + (size_t)CH * NPAIR * KVSZ;
    // frag overlays partial slab 0 (partial is dead once kv_reduce has run)
    uint4* frag = (uint4*)d_ws;

    kv_partial_kernel<<<dim3(NPAIR * CH * VSP), dim3(128), 0, stream>>>(K, V, kvm, partial, CH);
    kv_reduce_kernel<<<dim3((NPAIR * KVSZ + 255) / 256), dim3(256), 0, stream>>>(partial, kvf, CH);
    kv_pack_kernel<<<dim3(NPAIR), dim3(256), 0, stream>>>(kvf, frag);
    attn_out_kernel<<<dim3(NPAIR * 32), dim3(256), 0, stream>>>(Q, qm, frag, out);
}